// Round 1
// baseline (701.957 us; speedup 1.0000x reference)
//
#include <hip/hip_runtime.h>
#include <hip/hip_fp16.h>

typedef _Float16 f16;
typedef f16 f16x8 __attribute__((ext_vector_type(8)));
typedef f16 f16x4 __attribute__((ext_vector_type(4)));
typedef float f32x4 __attribute__((ext_vector_type(4)));

#define D_DIM 256
#define L_DIM 200
#define LPAD 208   // 13 * 16
#define HSTR 260   // fp16 row stride: 256 + 4 pad -> rows {0,4,8,12} land on banks {0,8,16,24}

// Convert both weight matrices to fp16 in workspace (re-run every launch; ws is re-poisoned).
__global__ void prep_w16(const float* __restrict__ Wm, const float* __restrict__ Wn,
                         f16* __restrict__ w16) {
    int i = blockIdx.x * 256 + threadIdx.x;   // 0 .. 65535
    w16[i] = (f16)Wm[i];
    w16[D_DIM * D_DIM + i] = (f16)Wn[i];
}

__global__ __launch_bounds__(512, 2)
void fused_cls_attn(const float* __restrict__ M, const float* __restrict__ N,
                    const float* __restrict__ act_r,
                    const float* __restrict__ bm, const float* __restrict__ bn,
                    const f16* __restrict__ w16,
                    float* __restrict__ out) {
    const int b  = blockIdx.x;
    const int br = blockIdx.y;
    const float* __restrict__ X    = (br == 0 ? M : N) + (size_t)b * (L_DIM * D_DIM);
    const f16*   __restrict__ W    = w16 + br * (D_DIM * D_DIM);
    const float* __restrict__ bias = (br == 0) ? bm : bn;

    __shared__ f16   Hs[LPAD * HSTR];     // 108160 B, H as fp16
    __shared__ float scores[LPAD];
    __shared__ float att[LPAD];
    __shared__ float part[8][D_DIM];      // out-phase partials
    __shared__ float red[16];

    const int tid  = threadIdx.x;
    const int lane = tid & 63;
    const int wv   = tid >> 6;            // 0..7, owns cols [wv*32, wv*32+32)
    const int r16  = lane & 15;
    const int g    = lane >> 4;           // 0..3

    if (tid < LPAD) scores[tid] = 0.f;

    // ---- preload B fragments (W rows, k-contiguous 8 per lane), act_r, bias ----
    f16x8 Bf[2][8];
    float arv[2], bv[2];
    #pragma unroll
    for (int nt = 0; nt < 2; ++nt) {
        const int col = wv * 32 + nt * 16 + r16;
        arv[nt] = act_r[b * D_DIM + col];
        bv[nt]  = bias[col];
        #pragma unroll
        for (int ks = 0; ks < 8; ++ks)
            Bf[nt][ks] = *(const f16x8*)(W + col * D_DIM + ks * 32 + g * 8);
    }
    __syncthreads();   // scores init visible before atomics

    // ---- GEMM + bias + ReLU + score partials, M-tile at a time ----
    for (int mt = 0; mt < 13; ++mt) {
        const int arow = mt * 16 + r16;
        // clamp row for the tail tile (rows 200..207 load row 199; excluded later)
        const float* __restrict__ xr = X + (size_t)(arow < L_DIM ? arow : L_DIM - 1) * D_DIM;
        f16x8 Af[8];
        #pragma unroll
        for (int ks = 0; ks < 8; ++ks) {
            f32x4 x0 = *(const f32x4*)(xr + ks * 32 + g * 8);
            f32x4 x1 = *(const f32x4*)(xr + ks * 32 + g * 8 + 4);
            f16x8 a;
            a[0] = (f16)x0[0]; a[1] = (f16)x0[1]; a[2] = (f16)x0[2]; a[3] = (f16)x0[3];
            a[4] = (f16)x1[0]; a[5] = (f16)x1[1]; a[6] = (f16)x1[2]; a[7] = (f16)x1[3];
            Af[ks] = a;
        }
        float sc[4] = {0.f, 0.f, 0.f, 0.f};
        #pragma unroll
        for (int nt = 0; nt < 2; ++nt) {
            f32x4 acc = {0.f, 0.f, 0.f, 0.f};
            #pragma unroll
            for (int ks = 0; ks < 8; ++ks)
                acc = __builtin_amdgcn_mfma_f32_16x16x32_f16(Af[ks], Bf[nt][ks], acc, 0, 0, 0);
            // C/D layout: col = lane&15, row = (lane>>4)*4 + reg (m89-verified)
            const int colc = wv * 32 + nt * 16 + r16;
            #pragma unroll
            for (int r = 0; r < 4; ++r) {
                const int rr = mt * 16 + g * 4 + r;
                float h = acc[r] + bv[nt];
                h = h > 0.f ? h : 0.f;
                Hs[rr * HSTR + colc] = (f16)h;
                if (rr < L_DIM) sc[r] += h * arv[nt];
            }
        }
        // reduce score partials across the 16 lanes of each row-group
        #pragma unroll
        for (int r = 0; r < 4; ++r) {
            float v = sc[r];
            v += __shfl_xor(v, 1);
            v += __shfl_xor(v, 2);
            v += __shfl_xor(v, 4);
            v += __shfl_xor(v, 8);
            const int rr = mt * 16 + g * 4 + r;
            if (r16 == 0 && rr < L_DIM) atomicAdd(&scores[rr], v);
        }
    }
    __syncthreads();

    // ---- softmax over L=200 ----
    const float s = (tid < L_DIM) ? scores[tid] : -3.0e38f;
    float mx = s;
    #pragma unroll
    for (int sh = 32; sh >= 1; sh >>= 1) mx = fmaxf(mx, __shfl_xor(mx, sh));
    if (lane == 0) red[wv] = mx;
    __syncthreads();
    if (tid == 0) {
        float mm = red[0];
        #pragma unroll
        for (int i = 1; i < 8; ++i) mm = fmaxf(mm, red[i]);
        red[8] = mm;
    }
    __syncthreads();
    const float bmax = red[8];
    const float e = (tid < L_DIM) ? __expf(s - bmax) : 0.f;
    if (tid < LPAD) att[tid] = e;
    float z = e;
    #pragma unroll
    for (int sh = 32; sh >= 1; sh >>= 1) z += __shfl_xor(z, sh);
    __syncthreads();                       // everyone done reading red[8]
    if (lane == 0) red[wv] = z;
    __syncthreads();
    if (tid == 0) {
        float zz = 0.f;
        #pragma unroll
        for (int i = 0; i < 8; ++i) zz += red[i];
        red[9] = 1.f / (zz * (float)L_DIM);   // fold the /L into the normalization
    }
    __syncthreads();
    const float scale = red[9];

    // ---- out[e] = sum_l att[l] * H[l][e], 8 row-quarters x 64 col-groups ----
    {
        const int colq = (tid & 63) * 4;
        const int q    = tid >> 6;            // 25 rows each, 8*25 = 200
        float a0 = 0.f, a1 = 0.f, a2 = 0.f, a3 = 0.f;
        const int l0 = q * 25;
        #pragma unroll
        for (int l = l0; l < l0 + 25; ++l) {
            const float al = att[l];
            f16x4 hv = *(const f16x4*)(&Hs[l * HSTR + colq]);
            a0 += al * (float)hv[0];
            a1 += al * (float)hv[1];
            a2 += al * (float)hv[2];
            a3 += al * (float)hv[3];
        }
        part[q][colq + 0] = a0;
        part[q][colq + 1] = a1;
        part[q][colq + 2] = a2;
        part[q][colq + 3] = a3;
    }
    __syncthreads();
    if (tid < D_DIM) {
        float sum = 0.f;
        #pragma unroll
        for (int qq = 0; qq < 8; ++qq) sum += part[qq][tid];
        out[(size_t)b * (2 * D_DIM) + br * D_DIM + tid] = sum * scale;
    }
}

extern "C" void kernel_launch(void* const* d_in, const int* in_sizes, int n_in,
                              void* d_out, int out_size, void* d_ws, size_t ws_size,
                              hipStream_t stream) {
    const float* M     = (const float*)d_in[0];
    const float* N     = (const float*)d_in[1];
    const float* act_r = (const float*)d_in[2];
    const float* Wm    = (const float*)d_in[3];
    const float* bm    = (const float*)d_in[4];
    const float* Wn    = (const float*)d_in[5];
    const float* bn    = (const float*)d_in[6];
    float* out = (float*)d_out;
    f16* w16 = (f16*)d_ws;   // 2 * 65536 fp16 = 256 KB

    const int B = in_sizes[2] / D_DIM;   // 1024

    prep_w16<<<D_DIM * D_DIM / 256, 256, 0, stream>>>(Wm, Wn, w16);
    dim3 grid(B, 2);
    fused_cls_attn<<<grid, 512, 0, stream>>>(M, N, act_r, bm, bn, w16, out);
}